// Round 8
// baseline (76.440 us; speedup 1.0000x reference)
//
#include <hip/hip_runtime.h>

#define SUBS  64
#define THIST 200
#define BT    64               // output rows per block
#define HALO  208              // window halo (>=200, multiple of 16)
#define WIN   (BT + HALO)      // 272 rows = 17 MFMA tiles
#define NTILE (WIN / 16)       // 17
#define HTILE (HALO / 16)      // 13 halo tiles
#define NPAIR 100              // tap pairs
#define WROW  137              // words per s-row: 136 pairs + 1 pad (odd -> conflict-free)

typedef _Float16 h2    __attribute__((ext_vector_type(2)));
typedef _Float16 f16x8 __attribute__((ext_vector_type(8)));
typedef float    f32x4 __attribute__((ext_vector_type(4)));
union uh2 { uint u; h2 h; };

__device__ inline short f2hs(float v) {
    union { _Float16 h; short s; } u; u.h = (_Float16)v; return u.s;
}
__device__ inline uint pkh2(float a, float b) {
    union { _Float16 h[2]; uint u; } p;
    p.h[0] = (_Float16)a; p.h[1] = (_Float16)b; return p.u;
}
__device__ inline f16x8 ld_frag(const float* p) {
    float4 a = *(const float4*)p;
    float4 b = *(const float4*)(p + 4);
    f16x8 f;
    f[0]=(_Float16)a.x; f[1]=(_Float16)a.y; f[2]=(_Float16)a.z; f[3]=(_Float16)a.w;
    f[4]=(_Float16)b.x; f[5]=(_Float16)b.y; f[6]=(_Float16)b.z; f[7]=(_Float16)b.w;
    return f;
}

// ---------------------------------------------------------------------------
// Kernel 1: reversed, pre-paired taps, transposed: krt[s*100+p] =
// pack(kern[s][199-2p], kern[s][198-2p]) as 2x f16.
// ---------------------------------------------------------------------------
__device__ inline float kval(int k, float del, const float* Ks, const float* tau) {
    float t = fmaxf((float)k - del, 0.0f);
    float v = 0.0f;
    #pragma unroll
    for (int b = 0; b < 3; ++b) {
        float tt = t / __expf(tau[b]);
        v = fmaf(tt * __expf(-tt), Ks[b], v);
    }
    return v;
}

__global__ __launch_bounds__(256) void k_taps(
    const float* __restrict__ K_spike, const float* __restrict__ tau_spike,
    const float* __restrict__ delta_spike, uint* __restrict__ krt)
{
    int idx = blockIdx.x * 256 + threadIdx.x;
    if (idx >= NPAIR * SUBS) return;
    int p = idx >> 6, s = idx & 63;
    float del = delta_spike[s];
    float Ks[3] = { K_spike[s*3], K_spike[s*3+1], K_spike[s*3+2] };
    float tl[3] = { tau_spike[0], tau_spike[1], tau_spike[2] };
    ushort lo = (ushort)f2hs(kval(199 - 2*p, del, Ks, tl));
    ushort hi = (ushort)f2hs(kval(198 - 2*p, del, Ks, tl));
    krt[s * 100 + p] = (uint)lo | ((uint)hi << 16);
}

// ---------------------------------------------------------------------------
// Fused kernel: per block of 64 output rows,
//   phase 1 (MFMA): window Zc = Z@C^T written TRANSPOSED into LDS directly
//     from D-fragments (lane holds 4 consecutive t of one s -> 2 f16-pair
//     words); output-tile accY bounced through the same region first and
//     read back as xb[8] per-lane pairs (base never touches global).
//   phase 2 (conv): dot2 FIR with rotating E/O pair windows + fenced
//     ping-pong tap/window prefetch; epilogue sigmoid from registers.
// ---------------------------------------------------------------------------
#define GROUP8(nE, kv)                                                          \
    _Pragma("unroll")                                                           \
    for (int j = 0; j < 8; ++j) {                                               \
        O[(j + 7) & 7] = __builtin_amdgcn_alignbit(nE[j], E[(j + 7) & 7], 16);  \
        uh2 kk; kk.u = kv[j];                                                   \
        _Pragma("unroll")                                                       \
        for (int i = 0; i < 8; ++i) {                                           \
            uh2 e; e.u = E[(j + i) & 7];                                        \
            uh2 o; o.u = O[(j + i) & 7];                                        \
            acc[2 * i]     = __builtin_amdgcn_fdot2(kk.h, e.h, acc[2 * i],     false); \
            acc[2 * i + 1] = __builtin_amdgcn_fdot2(kk.h, o.h, acc[2 * i + 1], false); \
        }                                                                       \
        E[j & 7] = nE[j];                                                       \
    }

#define LOADW8(nE, g) {                                                         \
    _Pragma("unroll")                                                           \
    for (int j = 0; j < 8; ++j) nE[j] = wp[q0 + (g) * 8 + 8 + j]; }

#define LOADK8(kv, g) {                                                         \
    uint4 _a = *(const uint4*)(tp0 + (g) * 8);                                  \
    uint4 _b = *(const uint4*)(tp0 + (g) * 8 + 4);                              \
    kv[0]=_a.x; kv[1]=_a.y; kv[2]=_a.z; kv[3]=_a.w;                             \
    kv[4]=_b.x; kv[5]=_b.y; kv[6]=_b.z; kv[7]=_b.w; }

__global__ __launch_bounds__(256, 4) void k_fused(
    const float* __restrict__ Z, const float* __restrict__ Y,
    const float* __restrict__ S, const float* __restrict__ C,
    const float* __restrict__ theta, const uint* __restrict__ krt,
    const float* __restrict__ W, const float* __restrict__ Vo,
    float* __restrict__ out, int T)
{
    __shared__ uint wzu[SUBS * WROW];        // 35072 B -> 4 blocks/CU
    const int tid  = threadIdx.x;
    const int lane = tid & 63;
    const int wv   = tid >> 6;               // 0..3
    const int lr   = lane & 15;
    const int lg   = lane >> 4;
    const int t0   = blockIdx.x * BT;

    // ---- B fragments from C: B[j][s] = C[s][j]
    f16x8 bfr[4][2];
    #pragma unroll
    for (int nt = 0; nt < 4; ++nt)
        #pragma unroll
        for (int ks = 0; ks < 2; ++ks)
            bfr[nt][ks] = ld_frag(&C[(lr + 16 * nt) * 64 + ks * 32 + lg * 8]);

    // ---- output tile (tile HTILE+wv, rows t0+16*wv .. +15)
    const int otile = HTILE + wv;
    const int orow  = t0 + 16 * wv;
    const int arow  = orow + lr;
    const bool okO  = arow < T;

    // Y part first: accY -> window bounce -> xb
    {
        f16x8 afr[2];
        #pragma unroll
        for (int ks = 0; ks < 2; ++ks)
            afr[ks] = okO ? ld_frag(&Y[(size_t)arow * 64 + ks * 32 + lg * 8])
                          : (f16x8)(_Float16)0.f;
        f32x4 accY[4];
        #pragma unroll
        for (int nt = 0; nt < 4; ++nt) accY[nt] = (f32x4){0,0,0,0};
        #pragma unroll
        for (int nt = 0; nt < 4; ++nt)
            #pragma unroll
            for (int ks = 0; ks < 2; ++ks)
                accY[nt] = __builtin_amdgcn_mfma_f32_16x16x32_f16(afr[ks], bfr[nt][ks], accY[nt], 0, 0, 0);
        #pragma unroll
        for (int nt = 0; nt < 4; ++nt) {
            const int w0 = (lr + 16 * nt) * WROW + 8 * otile + 2 * lg;
            wzu[w0]     = pkh2(accY[nt][0], accY[nt][1]);
            wzu[w0 + 1] = pkh2(accY[nt][2], accY[nt][3]);
        }
    }
    __builtin_amdgcn_wave_barrier();
    uint xb[8];
    #pragma unroll
    for (int k = 0; k < 8; ++k) xb[k] = wzu[lane * WROW + 8 * otile + k];
    __builtin_amdgcn_wave_barrier();

    // preload S rows for the epilogue (hides under rest of MFMA + conv)
    const int rt = 16 * wv;
    float sreg[16];
    #pragma unroll
    for (int r = 0; r < 16; ++r) {
        const int t = t0 + rt + r;
        sreg[r] = (t < T) ? S[(size_t)t * 64 + lane] : 0.f;
    }

    // Z part of output tile (overwrites bounce region with real Zc)
    {
        f16x8 afr[2];
        #pragma unroll
        for (int ks = 0; ks < 2; ++ks)
            afr[ks] = okO ? ld_frag(&Z[(size_t)arow * 64 + ks * 32 + lg * 8])
                          : (f16x8)(_Float16)0.f;
        f32x4 accZ[4];
        #pragma unroll
        for (int nt = 0; nt < 4; ++nt) accZ[nt] = (f32x4){0,0,0,0};
        #pragma unroll
        for (int nt = 0; nt < 4; ++nt)
            #pragma unroll
            for (int ks = 0; ks < 2; ++ks)
                accZ[nt] = __builtin_amdgcn_mfma_f32_16x16x32_f16(afr[ks], bfr[nt][ks], accZ[nt], 0, 0, 0);
        #pragma unroll
        for (int nt = 0; nt < 4; ++nt) {
            const int w0 = (lr + 16 * nt) * WROW + 8 * otile + 2 * lg;
            wzu[w0]     = pkh2(accZ[nt][0], accZ[nt][1]);
            wzu[w0 + 1] = pkh2(accZ[nt][2], accZ[nt][3]);
        }
    }

    // halo tiles j = wv, wv+4, ... < 13
    for (int j = wv; j < HTILE; j += 4) {
        const int row = t0 - HALO + 16 * j + lr;
        const bool ok = (row >= 0) && (row < T);
        f16x8 afr[2];
        #pragma unroll
        for (int ks = 0; ks < 2; ++ks)
            afr[ks] = ok ? ld_frag(&Z[(size_t)row * 64 + ks * 32 + lg * 8])
                         : (f16x8)(_Float16)0.f;
        f32x4 accZ[4];
        #pragma unroll
        for (int nt = 0; nt < 4; ++nt) accZ[nt] = (f32x4){0,0,0,0};
        #pragma unroll
        for (int nt = 0; nt < 4; ++nt)
            #pragma unroll
            for (int ks = 0; ks < 2; ++ks)
                accZ[nt] = __builtin_amdgcn_mfma_f32_16x16x32_f16(afr[ks], bfr[nt][ks], accZ[nt], 0, 0, 0);
        #pragma unroll
        for (int nt = 0; nt < 4; ++nt) {
            const int w0 = (lr + 16 * nt) * WROW + 8 * j + 2 * lg;
            wzu[w0]     = pkh2(accZ[nt][0], accZ[nt][1]);
            wzu[w0 + 1] = pkh2(accZ[nt][2], accZ[nt][3]);
        }
    }
    __syncthreads();

    // ---- conv phase: lane = s, 16 rows per wave
    const int q0 = (HALO - THIST) / 2 + 8 * wv;     // 4 + 8*wv
    const uint* wp  = &wzu[lane * WROW];
    const uint* tp0 = krt + lane * 100;

    float acc[16];
    #pragma unroll
    for (int r = 0; r < 16; ++r) acc[r] = 0.f;

    uint E[8], O[8];
    #pragma unroll
    for (int i = 0; i < 8; ++i) E[i] = wp[q0 + i];
    #pragma unroll
    for (int i = 0; i < 7; ++i) O[i] = __builtin_amdgcn_alignbit(E[i + 1], E[i], 16);

    uint Ea[8], Ka[8], Eb[8], Kb[8];
    LOADW8(Ea, 0); LOADK8(Ka, 0);

    #pragma unroll 1
    for (int gg = 0; gg < 5; ++gg) {
        const int g = 2 * gg;
        LOADW8(Eb, g + 1); LOADK8(Kb, g + 1);
        __builtin_amdgcn_sched_barrier(0);
        GROUP8(Ea, Ka);
        LOADW8(Ea, g + 2); LOADK8(Ka, g + 2);
        __builtin_amdgcn_sched_barrier(0);
        GROUP8(Eb, Kb);
    }
    LOADW8(Eb, 11); LOADK8(Kb, 11);
    __builtin_amdgcn_sched_barrier(0);
    GROUP8(Ea, Ka);                          // group 10
    {
        #pragma unroll
        for (int j = 0; j < 4; ++j) Ea[j] = wp[q0 + 104 + j];
        uint4 _a = *(const uint4*)(tp0 + 96);
        Ka[0]=_a.x; Ka[1]=_a.y; Ka[2]=_a.z; Ka[3]=_a.w;
    }
    __builtin_amdgcn_sched_barrier(0);
    GROUP8(Eb, Kb);                          // group 11
    #pragma unroll
    for (int j = 0; j < 4; ++j) {            // tail: pairs 96..99
        O[(j + 7) & 7] = __builtin_amdgcn_alignbit(Ea[j], E[(j + 7) & 7], 16);
        uh2 kk; kk.u = Ka[j];
        #pragma unroll
        for (int i = 0; i < 8; ++i) {
            uh2 e; e.u = E[(j + i) & 7];
            uh2 o; o.u = O[(j + i) & 7];
            acc[2 * i]     = __builtin_amdgcn_fdot2(kk.h, e.h, acc[2 * i],     false);
            acc[2 * i + 1] = __builtin_amdgcn_fdot2(kk.h, o.h, acc[2 * i + 1], false);
        }
        E[j & 7] = Ea[j];
    }

    // ---- epilogue: xin = accY(xb) + S + theta + conv; out = sigmoid*W + Vo
    const float wsub = W[lane];
    const float vo   = Vo[0];
    const float th   = theta[lane];
    #pragma unroll
    for (int k = 0; k < 8; ++k) {
        uh2 bb; bb.u = xb[k];
        #pragma unroll
        for (int h = 0; h < 2; ++h) {
            const int r = 2 * k + h;
            const int t = t0 + rt + r;
            if (t < T) {
                float xin = (float)bb.h[h] + sreg[r] + th + acc[r];
                float sig = 1.0f / (1.0f + __expf(-xin));
                out[(size_t)t * 64 + lane] = fmaf(sig, wsub, vo);
            }
        }
    }
}

// ---------------------------------------------------------------------------
extern "C" void kernel_launch(void* const* d_in, const int* in_sizes, int n_in,
                              void* d_out, int out_size, void* d_ws, size_t ws_size,
                              hipStream_t stream)
{
    const float* S     = (const float*)d_in[0];
    const float* Y     = (const float*)d_in[1];
    const float* Z     = (const float*)d_in[2];
    const float* C     = (const float*)d_in[3];
    const float* Vo    = (const float*)d_in[4];
    const float* W     = (const float*)d_in[5];
    const float* theta = (const float*)d_in[6];
    const float* K     = (const float*)d_in[7];
    const float* tau   = (const float*)d_in[8];
    const float* delta = (const float*)d_in[9];
    const int T = in_sizes[0] / SUBS;

    uint* krt = (uint*)d_ws;                                  // 25600 B

    k_taps<<<(NPAIR * SUBS + 255) / 256, 256, 0, stream>>>(K, tau, delta, krt);
    k_fused<<<(T + BT - 1) / BT, 256, 0, stream>>>(Z, Y, S, C, theta, krt, W, Vo,
                                                   (float*)d_out, T);
}